// Round 10
// baseline (599.391 us; speedup 1.0000x reference)
//
#include <hip/hip_runtime.h>
#include <math.h>

#define D 128
#define EPS 1e-6f
#define SKR_LD 136             // retrieve kernel (unchanged, proven)

typedef __attribute__((ext_vector_type(8))) short short8;
typedef __attribute__((ext_vector_type(4))) float f32x4;
typedef unsigned short ushort_t;
typedef unsigned long long u64;

__device__ __forceinline__ float elu1(float x) {
    float e = __expf(fminf(x, 0.f));
    return x > 0.f ? x + 1.f : e;
}
__device__ __forceinline__ unsigned short bf16rne(float f) {
    unsigned u = __builtin_bit_cast(unsigned, f);
    u += 0x7FFFu + ((u >> 16) & 1u);
    return (unsigned short)(u >> 16);
}
__device__ __forceinline__ float bf2f(unsigned short h) {
    unsigned u = (unsigned)h << 16;
    return __builtin_bit_cast(float, u);
}
__device__ __forceinline__ u64 pack4(float a, float b, float c, float d) {
    return (u64)bf16rne(a) | ((u64)bf16rne(b) << 16) |
           ((u64)bf16rne(c) << 32) | ((u64)bf16rne(d) << 48);
}
// packed f32->bf16 pair (dst.lo = a, dst.hi = b); no builtin on gfx950
__device__ __forceinline__ unsigned pk2(float a, float b) {
    unsigned r;
    asm("v_cvt_pk_bf16_f32 %0, %1, %2" : "=v"(r) : "v"(a), "v"(b));
    return r;
}

typedef union { short8 s8; unsigned u[4]; } apk_u;

// ---------------------------------------------------------------------------
// Update, barrier-free: per (bh,ch,zs) accumulate (for e-half zs)
//   pP = sigma^T V,  pG = sigma^T diag(1/(sigma.z+eps)) sigma,  pz = sum sigma
// NO LDS tiles, NO barriers, NO transposes: each lane loads its MFMA
// fragments directly from global (s-axis in-register; 16-lane 64B segments,
// L2-served).  Norm: p[j] accumulated over dt in-register, then a 4-level
// shfl reduce within the 16-lane g-group leaves row (8g+j)'s full dot in
// reg j — exactly the k-index the G B-frag needs.  Waves fully independent.
// Wave roles: w=t>>6: dh=w>>2 (dt-half), e-tile = 4*zs + (w&3).
// acc = 32 AGPR/wave; launch_bounds(512,2) -> no forced VGPR cap (rounds 5/9
// showed forced caps spill catastrophically; VGPR ~150 expected).
// ---------------------------------------------------------------------------
__global__ __launch_bounds__(512, 2)
void k_update(const float* __restrict__ key, const float* __restrict__ value,
              const float* __restrict__ zv,
              float* __restrict__ pP, float* __restrict__ pG,
              float* __restrict__ pz, int S)
{
    const int t = threadIdx.x;
    const int bh = blockIdx.x, ch = blockIdx.y, zs = blockIdx.z;
    const int NCH = gridDim.y;
    const int SC = S / NCH, NB = SC / 32, s0g = ch * SC;

    const int w = t >> 6, g = (t >> 4) & 3, m = t & 15;
    const int dh = w >> 2;            // this wave's dt-half (dt = 4*dh + dtl)
    const int et = 4 * zs + (w & 3);  // this wave's e-tile (0..7)
    const int ecol = 16 * et + m;

    const float* Kb = key   + (size_t)bh * S * D;
    const float* Vb = value + (size_t)bh * S * D;
    const float* zb = zv + (size_t)bh * D;

    // z values for this lane's d-columns (loop-invariant)
    float zreg[8];
    #pragma unroll
    for (int dt = 0; dt < 8; ++dt) zreg[dt] = zb[16 * dt + m];

    f32x4 accP[4], accG[4];
    #pragma unroll
    for (int i = 0; i < 4; ++i) { accP[i] = 0.f; accG[i] = 0.f; }
    float zacc[8] = {0.f, 0.f, 0.f, 0.f, 0.f, 0.f, 0.f, 0.f};

    for (int b = 0; b < NB; ++b) {
        const int s0 = s0g + 32 * b + 8 * g;       // this lane's 8 rows
        const float* kp = Kb + (size_t)s0 * D + m;
        const float* vp = Vb + (size_t)s0 * D + ecol;

        // V fragment loads (issue early; 64B segments per 16 lanes)
        float vv[8];
        #pragma unroll
        for (int j = 0; j < 8; ++j) vv[j] = vp[(size_t)j * D];

        float p[8] = {0.f, 0.f, 0.f, 0.f, 0.f, 0.f, 0.f, 0.f};
        apk_u apk[4], bgp;

        #pragma unroll
        for (int dt = 0; dt < 8; ++dt) {
            float sv[8];
            #pragma unroll
            for (int j = 0; j < 8; ++j)
                sv[j] = elu1(kp[(size_t)j * D + 16 * dt]);
            float za = 0.f;
            #pragma unroll
            for (int j = 0; j < 8; ++j) {
                p[j] = fmaf(sv[j], zreg[dt], p[j]);
                za += sv[j];
            }
            zacc[dt] += za;
            apk_u cur;
            cur.u[0] = pk2(sv[0], sv[1]); cur.u[1] = pk2(sv[2], sv[3]);
            cur.u[2] = pk2(sv[4], sv[5]); cur.u[3] = pk2(sv[6], sv[7]);
            if ((dt >> 2) == dh) apk[dt & 3] = cur;   // wave-uniform select
            if (dt == et) bgp = cur;                  // wave-uniform select
        }

        // norm: reduce p[j] over the 16 lanes of this g-group; every lane
        // then holds rn for row (8g+j) in slot j — the B-frag k-index.
        #pragma unroll
        for (int j = 0; j < 8; ++j) {
            float x = p[j];
            x += __shfl_xor(x, 1, 64);
            x += __shfl_xor(x, 2, 64);
            x += __shfl_xor(x, 4, 64);
            x += __shfl_xor(x, 8, 64);
            p[j] = 1.f / (x + EPS);
        }

        // B-frags: bv = V column; bg = sigma-hat column (sigma * rn per k)
        apk_u bv, bg;
        bv.u[0] = pk2(vv[0], vv[1]); bv.u[1] = pk2(vv[2], vv[3]);
        bv.u[2] = pk2(vv[4], vv[5]); bv.u[3] = pk2(vv[6], vv[7]);
        #pragma unroll
        for (int k2 = 0; k2 < 4; ++k2) {
            float lo = bf2f((ushort_t)(bgp.u[k2] & 0xffffu)) * p[2 * k2];
            float hi = bf2f((ushort_t)(bgp.u[k2] >> 16))     * p[2 * k2 + 1];
            bg.u[k2] = pk2(lo, hi);
        }

        // 8 MFMAs (4 dt x {P,G}), all independent
        #pragma unroll
        for (int dtl = 0; dtl < 4; ++dtl) {
            accP[dtl] = __builtin_amdgcn_mfma_f32_16x16x32_bf16(apk[dtl].s8, bv.s8, accP[dtl], 0, 0, 0);
            accG[dtl] = __builtin_amdgcn_mfma_f32_16x16x32_bf16(apk[dtl].s8, bg.s8, accG[dtl], 0, 0, 0);
        }
    }

    // write partials (fp32); z-blocks write disjoint column halves
    float* pPb = pP + ((size_t)bh * NCH + ch) * (D * D);
    float* pGb = pG + ((size_t)bh * NCH + ch) * (D * D);
    #pragma unroll
    for (int dtl = 0; dtl < 4; ++dtl) {
        const int row0 = 16 * (4 * dh + dtl) + 4 * g;
        #pragma unroll
        for (int r = 0; r < 4; ++r) {
            pPb[(size_t)(row0 + r) * D + ecol] = accP[dtl][r];
            pGb[(size_t)(row0 + r) * D + ecol] = accG[dtl][r];
        }
    }

    // pz: every wave computed identical zacc (all load full sigma);
    // reduce across g-groups, write once per (bh,ch).
    #pragma unroll
    for (int dt = 0; dt < 8; ++dt) {
        float a2 = zacc[dt];
        a2 += __shfl_xor(a2, 16, 64);
        a2 += __shfl_xor(a2, 32, 64);
        if (zs == 0 && w == 0 && (t & 63) < 16)
            pz[((size_t)bh * NCH + ch) * D + 16 * dt + m] = a2;
    }
}

// ---------------------------------------------------------------------------
// Sum: Mtmp = M + sum_ch pP ; (gh,gl) = split-bf16 of -(sum_ch pG) ;
//      z_new = z + sum_ch pz          (unchanged, R8-proven)
// ---------------------------------------------------------------------------
__global__ void k_sum(const float* __restrict__ M, const float* __restrict__ z,
                      const float* __restrict__ pP, const float* __restrict__ pG,
                      const float* __restrict__ pz,
                      float* __restrict__ Mtmp, ushort_t* __restrict__ gh,
                      ushort_t* __restrict__ gl, float* __restrict__ znew, int NCH)
{
    const int bh = blockIdx.x, sl = blockIdx.y, t = threadIdx.x;
    const size_t base = (size_t)bh * D * D;
    for (int i = sl * 2048 + t; i < (sl + 1) * 2048; i += 256) {
        float sp = M[base + i];
        float sg = 0.f;
        for (int c = 0; c < NCH; ++c) {
            sp += pP[((size_t)bh * NCH + c) * (D * D) + i];
            sg += pG[((size_t)bh * NCH + c) * (D * D) + i];
        }
        Mtmp[base + i] = sp;
        float nG = -sg;
        unsigned short hi = bf16rne(nG);
        gh[base + i] = hi;
        gl[base + i] = bf16rne(nG - bf2f(hi));
    }
    if (sl == 0 && t < D) {
        float a = z[(size_t)bh * D + t];
        for (int c = 0; c < NCH; ++c) a += pz[((size_t)bh * NCH + c) * D + t];
        znew[(size_t)bh * D + t] = a;
    }
}

// ---------------------------------------------------------------------------
// GM: M_new = Mtmp + (gh+gl) @ M   (unchanged, R8-proven)
// ---------------------------------------------------------------------------
__global__ __launch_bounds__(256)
void k_gm(const float* __restrict__ M, const float* __restrict__ Mtmp,
          const ushort_t* __restrict__ gh, const ushort_t* __restrict__ gl,
          float* __restrict__ Mnew)
{
    const int bh = blockIdx.x, t = threadIdx.x;
    const int w2 = t >> 6, g = (t >> 4) & 3, m = t & 15;
    const float* Mb = M + (size_t)bh * D * D;
    const float* Tb = Mtmp + (size_t)bh * D * D;
    const ushort_t* ghb = gh + (size_t)bh * D * D;
    const ushort_t* glb = gl + (size_t)bh * D * D;
    float* Ob = Mnew + (size_t)bh * D * D;

    f32x4 acc[8][2];
    #pragma unroll
    for (int dt = 0; dt < 8; ++dt)
        #pragma unroll
        for (int p = 0; p < 2; ++p)
            #pragma unroll
            for (int r = 0; r < 4; ++r)
                acc[dt][p][r] = Tb[(size_t)(16 * dt + 4 * g + r) * D + 32 * w2 + 16 * p + m];

    #pragma unroll
    for (int ks = 0; ks < 4; ++ks) {
        short8 bm[2];
        #pragma unroll
        for (int p = 0; p < 2; ++p)
            #pragma unroll
            for (int j = 0; j < 8; ++j)
                bm[p][j] = (short)bf16rne(Mb[(size_t)(32 * ks + 8 * g + j) * D + 32 * w2 + 16 * p + m]);
        #pragma unroll
        for (int dt = 0; dt < 8; ++dt) {
            short8 ah = *(const short8*)&ghb[(size_t)(16 * dt + m) * D + 32 * ks + 8 * g];
            short8 al = *(const short8*)&glb[(size_t)(16 * dt + m) * D + 32 * ks + 8 * g];
            #pragma unroll
            for (int p = 0; p < 2; ++p) {
                acc[dt][p] = __builtin_amdgcn_mfma_f32_16x16x32_bf16(ah, bm[p], acc[dt][p], 0, 0, 0);
                acc[dt][p] = __builtin_amdgcn_mfma_f32_16x16x32_bf16(al, bm[p], acc[dt][p], 0, 0, 0);
            }
        }
    }

    #pragma unroll
    for (int dt = 0; dt < 8; ++dt)
        #pragma unroll
        for (int p = 0; p < 2; ++p)
            #pragma unroll
            for (int r = 0; r < 4; ++r)
                Ob[(size_t)(16 * dt + 4 * g + r) * D + 32 * w2 + 16 * p + m] = acc[dt][p][r];
}

// ---------------------------------------------------------------------------
// Retrieve: out = (sigma_q @ M_new) / (sigma_q @ z_new + eps)
// (unchanged since round 2 — proven correct, at memory floor)
// ---------------------------------------------------------------------------
__global__ __launch_bounds__(256, 2)
void k_retrieve(const float* __restrict__ query, const float* __restrict__ Mnew,
                const float* __restrict__ znew, float* __restrict__ out, int S)
{
    __shared__ alignas(16) ushort_t sqR[2][32 * SKR_LD];
    __shared__ float normsh[2][32];

    const int t  = threadIdx.x;
    const int bh = blockIdx.x, ch = blockIdx.y, NCH = gridDim.y;
    const int SC = S / NCH;
    const int NB = SC / 32;
    const int s0g = ch * SC;

    const int w = t >> 6, g = (t >> 4) & 3, m = t & 15;
    const int sb = t >> 5, db = t & 31;

    const float* Qb = query + (size_t)bh * S * D;
    const float* Mb = Mnew + (size_t)bh * D * D;
    const float* zb = znew + (size_t)bh * D;
    float*       Ob = out + (size_t)bh * S * D;

    float zr[4];
    #pragma unroll
    for (int j = 0; j < 4; ++j) zr[j] = zb[4 * db + j];

    short8 Bf[4][2];
    #pragma unroll
    for (int ks = 0; ks < 4; ++ks)
        #pragma unroll
        for (int p = 0; p < 2; ++p) {
            short8 f;
            #pragma unroll
            for (int j = 0; j < 8; ++j)
                f[j] = (short)bf16rne(Mb[(size_t)(32 * ks + 8 * g + j) * D + 16 * (2 * w + p) + m]);
            Bf[ks][p] = f;
        }

    auto STAGE_PROC = [&](const float4* qreg, int bu) {
        float sv[4][4];
        #pragma unroll
        for (int js = 0; js < 4; ++js) {
            sv[js][0] = elu1(qreg[js].x); sv[js][1] = elu1(qreg[js].y);
            sv[js][2] = elu1(qreg[js].z); sv[js][3] = elu1(qreg[js].w);
        }
        #pragma unroll
        for (int js = 0; js < 4; ++js)
            *(u64*)&sqR[bu][(4 * sb + js) * SKR_LD + 4 * db] =
                pack4(sv[js][0], sv[js][1], sv[js][2], sv[js][3]);
        float np[4];
        #pragma unroll
        for (int js = 0; js < 4; ++js)
            np[js] = sv[js][0] * zr[0] + sv[js][1] * zr[1] +
                     sv[js][2] * zr[2] + sv[js][3] * zr[3];
        #pragma unroll
        for (int mask = 16; mask >= 1; mask >>= 1) {
            np[0] += __shfl_xor(np[0], mask, 64);
            np[1] += __shfl_xor(np[1], mask, 64);
            np[2] += __shfl_xor(np[2], mask, 64);
            np[3] += __shfl_xor(np[3], mask, 64);
        }
        if (db < 4) {
            float v = db == 0 ? np[0] : db == 1 ? np[1] : db == 2 ? np[2] : np[3];
            normsh[bu][4 * sb + db] = v + EPS;
        }
    };

    {
        float4 qreg[4];
        #pragma unroll
        for (int js = 0; js < 4; ++js)
            qreg[js] = *(const float4*)&Qb[(size_t)(s0g + 4 * sb + js) * D + 4 * db];
        STAGE_PROC(qreg, 0);
    }
    __syncthreads();

    for (int b = 0; b < NB; ++b) {
        const int bu = b & 1;
        float4 qreg[4];
        if (b + 1 < NB) {
            #pragma unroll
            for (int js = 0; js < 4; ++js)
                qreg[js] = *(const float4*)&Qb[(size_t)(s0g + 32 * (b + 1) + 4 * sb + js) * D + 4 * db];
        }

        f32x4 mp[2][2];
        #pragma unroll
        for (int st = 0; st < 2; ++st)
            #pragma unroll
            for (int p = 0; p < 2; ++p) mp[st][p] = 0.f;
        #pragma unroll
        for (int st = 0; st < 2; ++st)
            #pragma unroll
            for (int ks = 0; ks < 4; ++ks) {
                short8 a = *(short8*)&sqR[bu][(16 * st + m) * SKR_LD + 32 * ks + 8 * g];
                #pragma unroll
                for (int p = 0; p < 2; ++p)
                    mp[st][p] = __builtin_amdgcn_mfma_f32_16x16x32_bf16(a, Bf[ks][p], mp[st][p], 0, 0, 0);
            }

        #pragma unroll
        for (int st = 0; st < 2; ++st)
            #pragma unroll
            for (int r = 0; r < 4; ++r) {
                float rn = 1.f / normsh[bu][16 * st + 4 * g + r];
                #pragma unroll
                for (int p = 0; p < 2; ++p)
                    Ob[(size_t)(s0g + 32 * b + 16 * st + 4 * g + r) * D + 16 * (2 * w + p) + m] =
                        mp[st][p][r] * rn;
            }

        if (b + 1 < NB) STAGE_PROC(qreg, (b + 1) & 1);
        __syncthreads();
    }
}

// ---------------------------------------------------------------------------
extern "C" void kernel_launch(void* const* d_in, const int* in_sizes, int n_in,
                              void* d_out, int out_size, void* d_ws, size_t ws_size,
                              hipStream_t stream)
{
    const float* q = (const float*)d_in[0];
    const float* k = (const float*)d_in[1];
    const float* v = (const float*)d_in[2];
    const float* M = (const float*)d_in[3];
    const float* z = (const float*)d_in[4];

    const int BH = in_sizes[3] / (D * D);
    const int S  = in_sizes[0] / (BH * D);
    const int NCH = 8;

    float* out  = (float*)d_out;
    float* Mnew = out + (size_t)BH * S * D;
    float* znew = Mnew + (size_t)BH * D * D;

    // Scratch in the front of `out` (fully overwritten by k_retrieve later;
    // stream-ordered so k_sum/k_gm read it first).  R8-proven.
    float* pP   = out;
    float* pG   = pP + (size_t)NCH * BH * D * D;
    float* pz   = pG + (size_t)NCH * BH * D * D;
    float* Mtmp = pz + (size_t)NCH * BH * D;
    ushort_t* gh = (ushort_t*)(Mtmp + (size_t)BH * D * D);
    ushort_t* gl = gh + (size_t)BH * D * D;

    dim3 gridA(BH, NCH, 2);
    k_update<<<gridA, 512, 0, stream>>>(k, v, z, pP, pG, pz, S);
    dim3 gridB(BH, 8);
    k_sum<<<gridB, 256, 0, stream>>>(M, z, pP, pG, pz, Mtmp, gh, gl, znew, NCH);
    k_gm<<<BH, 256, 0, stream>>>(M, Mtmp, gh, gl, Mnew);
    dim3 gridC(BH, 8);
    k_retrieve<<<gridC, 256, 0, stream>>>(q, Mnew, znew, out, S);
}